// Round 19
// baseline (203.404 us; speedup 1.0000x reference)
//
#include <hip/hip_runtime.h>
#include <math.h>

// TopKRouter: logits = x(16384x2048) @ W(2048x64) + b; softmax E=64; top-2.
// Output: d_out[0:32768] = indices (as float), d_out[32768:65536] = probs.
//
// R19: R10 schedule with ALL K-loop global loads as inline-asm
// global_load_dwordx4 + counted s_waitcnt vmcnt(N) (T4 pattern). R17 proved
// sched_barrier pins hold issue ORDER but not register LIVENESS (VGPR
// collapsed 110->52); asm "=&v" outputs force both: asm volatile can't sink,
// and outputs stay live issue->use. Steady state 24 loads in flight
// (96 VGPR pinned): vmcnt(8) before stepA (drains xA+W0), vmcnt(12) before
// stepB (drains W1), sched_barrier(0) after each wait (guide rule #18:
// MFMA hoists past asm waitcnt without it). Loop has no C++ memory ops ->
// no competing compiler waitcnts. Epilogue: vmcnt(0) + keep-alive asm so
// in-flight clamp loads can't land in reallocated regs. Numerics identical
// (absmax 2^-10). Signature if liveness held: VGPR_Count >= ~180.

#define D_DIM 2048
#define E_DIM 64
#define M_DIM 16384
#define RM 32             // token rows per block (2 row-groups x 16)

typedef _Float16 half8 __attribute__((ext_vector_type(8)));
typedef float floatx4 __attribute__((ext_vector_type(4)));
typedef unsigned int uint;

#define SBAR() __builtin_amdgcn_sched_barrier(0)
#define GLOAD4(dst, addr, off) \
    asm volatile("global_load_dwordx4 %0, %1, off offset:" #off \
                 : "=&v"(dst) : "v"(addr) : "memory")
#define VWAIT(n) asm volatile("s_waitcnt vmcnt(" #n ")" ::: "memory")

// ---------------- kernel 1: W split into fragment-linear layout (unchanged) ----
// For k-step g (32 k), tile t, plane p (0=hi,1=lo):
//   wsT[((g*4+t)*2+p)*512 + lane*8 + j] = plane(W[g*32 + quad*8 + j][16t + c]),
//   lane = quad*16 + c.
__global__ __launch_bounds__(256) void split_w_kernel(
    const float* __restrict__ Wm, _Float16* __restrict__ wsT)
{
    const int tid = threadIdx.x;
    const int n   = tid & 63;
    const int kk0 = tid >> 6;           // 0..3
    const int g   = blockIdx.x;         // 0..63
    #pragma unroll
    for (int r = 0; r < 8; r++) {
        const int kk = kk0 + r * 4;     // 0..31
        const float v = Wm[(size_t)(g * 32 + kk) * E_DIM + n];
        const _Float16 h = (_Float16)v;
        const _Float16 l = (_Float16)((v - (float)h) * 2048.0f);
        const int t = n >> 4, cc = n & 15, qd = kk >> 3, j = kk & 7;
        const size_t base = (size_t)((g * 4 + t) * 2) * 512 + (size_t)(qd * 16 + cc) * 8 + j;
        wsT[base]       = h;
        wsT[base + 512] = l;
    }
}

// ---------------- kernel 2: LDS-free MFMA GEMM + softmax + top-2 ----------------
__global__ __launch_bounds__(256, 2) void router_mfma_kernel(
    const float* __restrict__ x, const _Float16* __restrict__ wsT,
    const float* __restrict__ bias, float* __restrict__ out)
{
    __shared__ float red[4 * RM * 65];    // [kwave][row][expert(+pad)] 33280 B

    const int lane = threadIdx.x & 63;
    const int wave = threadIdx.x >> 6;    // k-split: wave w owns k in [w*512, w*512+512)
    const int c    = lane & 15;
    const int quad = lane >> 4;
    const int r0   = blockIdx.x * RM;
    const int kb   = wave * (D_DIM / 4);  // 512

    // x B-frag source: lane (c,quad) reads x[r0 + rg*16 + c][kb + u*32 + quad*8 .. +7]
    const float* xg0 = x + (size_t)(r0 + c) * D_DIM + kb + quad * 8;
    const float* xg1 = xg0 + (size_t)16 * D_DIM;
    // W A-frags: wsT[(wave*16 + u)*4096 + t*1024 + plane*512 + lane*8 + j]
    const _Float16* wbase = wsT + (size_t)(wave * 16) * 4096 + (size_t)lane * 8;

    floatx4 accm[2][4] = {};   // [row-group][expert tile]
    floatx4 accl[2][4] = {};

    floatx4 a0A, a1A, b0A, b1A;   // ping x regs (rg0 pair, rg1 pair)
    floatx4 a0B, a1B, b0B, b1B;   // pong
    floatx4 wh0[4], wl0[4], wh1[4], wl1[4];   // W frags as raw 16B tuples

    auto loadxA = [&](int u) {
        const int uu = u < 16 ? u : 15;
        const float* p0 = xg0 + (size_t)uu * 32;
        const float* p1 = xg1 + (size_t)uu * 32;
        GLOAD4(a0A, p0, 0); GLOAD4(a1A, p0, 16);
        GLOAD4(b0A, p1, 0); GLOAD4(b1A, p1, 16);
    };
    auto loadxB = [&](int u) {
        const int uu = u < 16 ? u : 15;
        const float* p0 = xg0 + (size_t)uu * 32;
        const float* p1 = xg1 + (size_t)uu * 32;
        GLOAD4(a0B, p0, 0); GLOAD4(a1B, p0, 16);
        GLOAD4(b0B, p1, 0); GLOAD4(b1B, p1, 16);
    };
    auto loadW = [&](int u, floatx4* wh, floatx4* wl) {   // u = local k-step 0..15
        const int uu = u < 16 ? u : 15;
        const _Float16* p  = wbase + (size_t)uu * 4096;
        const _Float16* p2 = p + 2048;                     // +4096 B
        // byte offsets: tile t at t*2048, lo plane +1024 (all <= 3072 < 4095)
        GLOAD4(wh[0], p,  0);    GLOAD4(wl[0], p,  1024);
        GLOAD4(wh[1], p,  2048); GLOAD4(wl[1], p,  3072);
        GLOAD4(wh[2], p2, 0);    GLOAD4(wl[2], p2, 1024);
        GLOAD4(wh[3], p2, 2048); GLOAD4(wl[3], p2, 3072);
    };
    // fp32x8 -> (hi fp16x8, lo fp16x8); h = RTZ-13-bit-masked (exact in fp16),
    // l = (v-h)*2048 (exact product of residual). Proven numerics (R5/R7/R10).
    auto mkfrag = [&](const floatx4& u0, const floatx4& u1, half8& h8, half8& l8) {
        const float f[8] = {u0[0], u0[1], u0[2], u0[3], u1[0], u1[1], u1[2], u1[3]};
        uint hq[4], lq[4];
        #pragma unroll
        for (int p = 0; p < 4; p++) {
            const float f0 = f[2 * p], f1 = f[2 * p + 1];
            const float h0 = __uint_as_float(__float_as_uint(f0) & 0xFFFFE000u);
            const float h1 = __uint_as_float(__float_as_uint(f1) & 0xFFFFE000u);
            hq[p] = __builtin_bit_cast(uint, __builtin_amdgcn_cvt_pkrtz(h0, h1));
            lq[p] = __builtin_bit_cast(uint,
                        __builtin_amdgcn_cvt_pkrtz((f0 - h0) * 2048.0f, (f1 - h1) * 2048.0f));
        }
        h8 = __builtin_bit_cast(half8, make_uint4(hq[0], hq[1], hq[2], hq[3]));
        l8 = __builtin_bit_cast(half8, make_uint4(lq[0], lq[1], lq[2], lq[3]));
    };
    // D = A(W) * B(x): accm/accl[rg][t]; split-3: Wh*xh -> m, Wh*xl + Wl*xh -> l
    auto stepA = [&](const floatx4* wh, const floatx4* wl) {
        half8 xh0, xl0, xh1, xl1;
        mkfrag(a0A, a1A, xh0, xl0);
        mkfrag(b0A, b1A, xh1, xl1);
        #pragma unroll
        for (int t = 0; t < 4; t++) {
            const half8 w_h = __builtin_bit_cast(half8, wh[t]);
            const half8 w_l = __builtin_bit_cast(half8, wl[t]);
            accm[0][t] = __builtin_amdgcn_mfma_f32_16x16x32_f16(w_h, xh0, accm[0][t], 0, 0, 0);
            accl[0][t] = __builtin_amdgcn_mfma_f32_16x16x32_f16(w_h, xl0, accl[0][t], 0, 0, 0);
            accl[0][t] = __builtin_amdgcn_mfma_f32_16x16x32_f16(w_l, xh0, accl[0][t], 0, 0, 0);
            accm[1][t] = __builtin_amdgcn_mfma_f32_16x16x32_f16(w_h, xh1, accm[1][t], 0, 0, 0);
            accl[1][t] = __builtin_amdgcn_mfma_f32_16x16x32_f16(w_h, xl1, accl[1][t], 0, 0, 0);
            accl[1][t] = __builtin_amdgcn_mfma_f32_16x16x32_f16(w_l, xh1, accl[1][t], 0, 0, 0);
        }
    };
    auto stepB = [&](const floatx4* wh, const floatx4* wl) {
        half8 xh0, xl0, xh1, xl1;
        mkfrag(a0B, a1B, xh0, xl0);
        mkfrag(b0B, b1B, xh1, xl1);
        #pragma unroll
        for (int t = 0; t < 4; t++) {
            const half8 w_h = __builtin_bit_cast(half8, wh[t]);
            const half8 w_l = __builtin_bit_cast(half8, wl[t]);
            accm[0][t] = __builtin_amdgcn_mfma_f32_16x16x32_f16(w_h, xh0, accm[0][t], 0, 0, 0);
            accl[0][t] = __builtin_amdgcn_mfma_f32_16x16x32_f16(w_h, xl0, accl[0][t], 0, 0, 0);
            accl[0][t] = __builtin_amdgcn_mfma_f32_16x16x32_f16(w_l, xh0, accl[0][t], 0, 0, 0);
            accm[1][t] = __builtin_amdgcn_mfma_f32_16x16x32_f16(w_h, xh1, accm[1][t], 0, 0, 0);
            accl[1][t] = __builtin_amdgcn_mfma_f32_16x16x32_f16(w_h, xl1, accl[1][t], 0, 0, 0);
            accl[1][t] = __builtin_amdgcn_mfma_f32_16x16x32_f16(w_l, xh1, accl[1][t], 0, 0, 0);
        }
    };

    // prologue: xA(0) 4, xB(1) 4, W0(0) 8  -> 16 loads in flight (invariant)
    loadxA(0);
    loadxB(1);
    loadW(0, wh0, wl0);

    #pragma unroll 1
    for (int u = 0; u < 16; u += 2) {
        loadW(u + 1, wh1, wl1);     // +8 -> 24 in flight
        VWAIT(8);                   // drain xA(u), xB(u+1), W0(u); W1 stays
        SBAR();                     // rule #18: MFMA must not hoist past wait
        stepA(wh0, wl0);            // k-step u
        loadxA(u + 2);              // +4 -> 12
        loadW(u + 2, wh0, wl0);     // +8 -> 20
        VWAIT(12);                  // drain W1(u+1); xA',W0' stay
        SBAR();
        stepB(wh1, wl1);            // k-step u+1
        loadxB(u + 3);              // +4 -> 16 (invariant restored)
    }

    // drain clamp/junk loads BEFORE their registers can be reallocated
    asm volatile("s_waitcnt vmcnt(0)" ::: "memory");
    asm volatile("" :: "v"(a0A), "v"(a1A), "v"(b0A), "v"(b1A),
                       "v"(a0B), "v"(a1B), "v"(b0B), "v"(b1B));
    asm volatile("" :: "v"(wh0[0]), "v"(wh0[1]), "v"(wh0[2]), "v"(wh0[3]),
                       "v"(wl0[0]), "v"(wl0[1]), "v"(wl0[2]), "v"(wl0[3]));
    asm volatile("" :: "v"(wh1[0]), "v"(wh1[1]), "v"(wh1[2]), "v"(wh1[3]),
                       "v"(wl1[0]), "v"(wl1[1]), "v"(wl1[2]), "v"(wl1[3]));

    // ---- K-split partials -> LDS ----
    const float scale = 1.0f / 2048.0f;
    #pragma unroll
    for (int rg = 0; rg < 2; rg++)
        #pragma unroll
        for (int t = 0; t < 4; t++)
            #pragma unroll
            for (int i = 0; i < 4; i++)
                red[(wave * 32 + rg * 16 + c) * 65 + t * 16 + quad * 4 + i] =
                    accm[rg][t][i] + accl[rg][t][i] * scale;
    __syncthreads();

    if (wave >= 2) return;

    float bvt[4];
    #pragma unroll
    for (int t = 0; t < 4; t++) bvt[t] = bias[c + 16 * t];

    #pragma unroll
    for (int i = 0; i < 4; i++) {
        const int row = wave * 16 + quad * 4 + i;
        float lt[4];
        #pragma unroll
        for (int t = 0; t < 4; t++) {
            const int col = c + 16 * t;
            lt[t] = red[(0 * 32 + row) * 65 + col] + red[(1 * 32 + row) * 65 + col]
                  + red[(2 * 32 + row) * 65 + col] + red[(3 * 32 + row) * 65 + col] + bvt[t];
        }
        const float l0 = lt[0], l1 = lt[1], l2 = lt[2], l3 = lt[3];

        float m = fmaxf(fmaxf(l0, l1), fmaxf(l2, l3));
        #pragma unroll
        for (int off = 1; off < 16; off <<= 1)
            m = fmaxf(m, __shfl_xor(m, off, 64));

        const float e0 = expf(l0 - m), e1 = expf(l1 - m);
        const float e2 = expf(l2 - m), e3 = expf(l3 - m);
        float s = e0 + e1 + e2 + e3;
        #pragma unroll
        for (int off = 1; off < 16; off <<= 1)
            s += __shfl_xor(s, off, 64);

        const float p0 = e0 / s, p1 = e1 / s, p2 = e2 / s, p3 = e3 / s;

        // keys: (prob bits << 32) | (63 - expert); experts c, c+16, c+32, c+48
        const unsigned long long ka =
            ((unsigned long long)__float_as_uint(p0) << 32) | (unsigned long long)(63 - c);
        const unsigned long long kb_ =
            ((unsigned long long)__float_as_uint(p1) << 32) | (unsigned long long)(47 - c);
        const unsigned long long kc_ =
            ((unsigned long long)__float_as_uint(p2) << 32) | (unsigned long long)(31 - c);
        const unsigned long long kd =
            ((unsigned long long)__float_as_uint(p3) << 32) | (unsigned long long)(15 - c);

        unsigned long long hi1 = ka > kb_ ? ka : kb_, lo1 = ka > kb_ ? kb_ : ka;
        unsigned long long hi2 = kc_ > kd ? kc_ : kd, lo2 = kc_ > kd ? kd : kc_;
        unsigned long long k1 = hi1 > hi2 ? hi1 : hi2;
        unsigned long long mn = hi1 > hi2 ? hi2 : hi1;
        unsigned long long mx = lo1 > lo2 ? lo1 : lo2;
        unsigned long long k2 = mn > mx ? mn : mx;

        #pragma unroll
        for (int off = 1; off < 16; off <<= 1) {
            const unsigned long long o1 = __shfl_xor(k1, off, 64);
            const unsigned long long o2 = __shfl_xor(k2, off, 64);
            const unsigned long long n1 = k1 > o1 ? k1 : o1;
            const unsigned long long w1 = k1 > o1 ? o1 : k1;   // loser of firsts
            const unsigned long long w2 = k2 > o2 ? k2 : o2;   // best of seconds
            k1 = n1;
            k2 = w1 > w2 ? w1 : w2;
        }

        if (c == 0) {
            const int gr = r0 + row;
            out[gr * 2 + 0] = (float)(63 - (int)(k1 & 0xFFFFFFFFull));
            out[gr * 2 + 1] = (float)(63 - (int)(k2 & 0xFFFFFFFFull));
            out[M_DIM * 2 + gr * 2 + 0] = __uint_as_float((unsigned)(k1 >> 32));
            out[M_DIM * 2 + gr * 2 + 1] = __uint_as_float((unsigned)(k2 >> 32));
        }
    }
}

extern "C" void kernel_launch(void* const* d_in, const int* in_sizes, int n_in,
                              void* d_out, int out_size, void* d_ws, size_t ws_size,
                              hipStream_t stream) {
    const float* x  = (const float*)d_in[0];
    const float* Wm = (const float*)d_in[1];
    const float* b  = (const float*)d_in[2];
    float* out = (float*)d_out;
    _Float16* wsT = (_Float16*)d_ws;   // 64*4*2*512*2 B = 512 KB

    split_w_kernel<<<dim3(64), dim3(256), 0, stream>>>(Wm, wsT);
    router_mfma_kernel<<<dim3(M_DIM / RM), dim3(256), 0, stream>>>(x, wsT, b, out);
}